// Round 14
// baseline (523.244 us; speedup 1.0000x reference)
//
#include <hip/hip_runtime.h>
#include <hip/hip_bf16.h>
#include <math.h>

#define NN 32768      // B*NPG nodes
#define BG 64         // graphs
#define NPGC 512      // nodes per graph
#define DD 128        // hidden dim
#define EE 524288     // edges
#define LL 10         // layers
#define EPSF 1e-5f
#define PADK 72       // LDS pitch (halfwords): 2-way bank aliasing only (free, m136)

typedef __attribute__((ext_vector_type(8))) short short8;
typedef __attribute__((ext_vector_type(4))) float float4v;

static __device__ __forceinline__ unsigned short f2bf(float x) {
    __hip_bfloat16 b = __float2bfloat16(x);
    return *reinterpret_cast<unsigned short*>(&b);
}
static __device__ __forceinline__ float bf2f(unsigned short u) {
    unsigned int v = ((unsigned int)u) << 16;
    return __uint_as_float(v);
}
// split x into hi+lo bf16 (residual <= 2^-18 |x|)
static __device__ __forceinline__ void splitbf(float x, unsigned short& h, unsigned short& l) {
    unsigned short hh = f2bf(x);
    h = hh;
    l = f2bf(x - bf2f(hh));
}

// XCD swizzle (confirmed R4): graph g work on blocks with blockIdx%8 == g%8.
// Aggregation: Adj = diag(dinv) M diag(dinv), M = A+I small-int -> u8 (exact),
// expanded to bf16 during staging. R14: B operand loaded DIRECTLY from global
// (L2-hot, k-contiguous 16B/lane) — no cross-wave B reuse inside a block, so
// LDS staging for B was pure overhead. Only A (4x cross-wave reuse) uses LDS.

// ---------------- prologue ----------------
// byte-packed histogram directly into Mu8 (4 cells per u32 atomic)
__global__ void k_histM(const int* __restrict__ src, const int* __restrict__ dst,
                        unsigned int* __restrict__ Mp, int* __restrict__ cnt) {
    int e = blockIdx.x * 256 + threadIdx.x;
    int d = dst[e], s = src[e] & 511;
    int cell = (d << 9) + s;
    atomicAdd(&Mp[cell >> 2], 1u << ((cell & 3) << 3));
    atomicAdd(&cnt[d], 1);
}

// +1 on each node's local diagonal, in place (runs after k_histM)
__global__ void k_diag(unsigned char* __restrict__ Mu8) {
    int n = blockIdx.x * 256 + threadIdx.x;
    Mu8[(size_t)n * 512 + (n & 511)] += 1;
}

__global__ void k_dinv(const int* __restrict__ cnt, float* __restrict__ dinv) {
    int n = blockIdx.x * 256 + threadIdx.x;
    dinv[n] = rsqrtf(1.0f + (float)cnt[n]);
}

// Wt[l][f'][f] = split(W_rest[l][f][f'])
__global__ void k_wt(const float* __restrict__ Wr, unsigned short* __restrict__ Wt_h,
                     unsigned short* __restrict__ Wt_l) {
    int idx = blockIdx.x * 256 + threadIdx.x;   // over 9*16384
    int l = idx >> 14, rem = idx & 16383;
    int fp = rem >> 7, f = rem & 127;
    unsigned short h, lo;
    splitbf(Wr[l * 16384 + f * 128 + fp], h, lo);
    Wt_h[idx] = h;
    Wt_l[idx] = lo;
}

// layer-0: hwT[f][n] = split(dinv[n] * x[n] * W0[f])
__global__ void k_l0(const float* __restrict__ x, const float* __restrict__ W0,
                     const float* __restrict__ dinv,
                     unsigned short* __restrict__ hwT_h, unsigned short* __restrict__ hwT_l) {
    int u = blockIdx.x * 256 + threadIdx.x;     // 128*4096 units of 8 nodes
    int f = u >> 12, n0 = (u & 4095) * 8;
    float w = W0[f];
    float4 xa = *(const float4*)(x + n0);
    float4 xb = *(const float4*)(x + n0 + 4);
    float4 da = *(const float4*)(dinv + n0);
    float4 db = *(const float4*)(dinv + n0 + 4);
    float v[8] = {xa.x * w * da.x, xa.y * w * da.y, xa.z * w * da.z, xa.w * w * da.w,
                  xb.x * w * db.x, xb.y * w * db.y, xb.z * w * db.z, xb.w * w * db.w};
    unsigned short uh[8], ul[8];
    #pragma unroll
    for (int i = 0; i < 8; i++) splitbf(v[i], uh[i], ul[i]);
    *(uint4*)(hwT_h + (size_t)f * NN + n0) = *(uint4*)uh;
    *(uint4*)(hwT_l + (size_t)f * NN + n0) = *(uint4*)ul;
}

// ---------------- aggregation: pre = diag(dinv) (M @ hwT^T) + bias ---------
// 256 blocks (4/graph, XCD-swizzled), 256 threads, 128 dst x 128 f, K=512,
// BK=64. LDS: A only (18.4KB). B fragments are direct 16B global loads
// (L2-hot, issued right after the A barrier so A-ds_reads + MFMAs hide their
// latency). 1 wave/SIMD -> ~512 VGPR budget, no spill risk.
__global__ __launch_bounds__(256) void k_aggmm(const unsigned char* __restrict__ Mu8,
        const unsigned short* __restrict__ hwT_h, const unsigned short* __restrict__ hwT_l,
        const float* __restrict__ dinv, const float* __restrict__ bias,
        float* __restrict__ pre, float* __restrict__ stats) {
    __shared__ unsigned short As[128 * PADK];    // 18.4KB (A only)
    int t = threadIdx.x, lane = t & 63, wv = t >> 6;
    int l15 = lane & 15, quad = lane >> 4;
    int b = blockIdx.x, r = b & 7, q = b >> 3;   // q: 0..31
    int g = r + 8 * (q & 7);
    int mb = (q >> 3) * 128;                     // 4 tiles of 128 dst per graph
    size_t arow = ((size_t)g * 512 + mb) * 512;  // byte offset into Mu8
    size_t gcol = (size_t)g * 512;
    int f0 = wv * 32;
    // per-lane B row bases (k-contiguous in hwT)
    const unsigned short* bp_h[2];
    const unsigned short* bp_l[2];
    #pragma unroll
    for (int nt = 0; nt < 2; nt++) {
        size_t rowoff = (size_t)(f0 + nt * 16 + l15) * NN + gcol;
        bp_h[nt] = hwT_h + rowoff;
        bp_l[nt] = hwT_l + rowoff;
    }
    float4v acc[16];         // [mt 0..7][nt 0..1]
    #pragma unroll
    for (int i = 0; i < 16; i++) acc[i] = (float4v)0.f;

    for (int kc = 0; kc < 512; kc += 64) {
        __syncthreads();
        #pragma unroll
        for (int i = 0; i < 4; i++) {            // A: 1024 units of 8 u8 cells
            int u = t + i * 256;
            int row = u >> 3, ko = (u & 7) * 8;
            uint2 w = *(const uint2*)(Mu8 + arow + (size_t)row * 512 + kc + ko);
            unsigned short us[8];
            us[0] = f2bf((float)(w.x & 0xffu));
            us[1] = f2bf((float)((w.x >> 8) & 0xffu));
            us[2] = f2bf((float)((w.x >> 16) & 0xffu));
            us[3] = f2bf((float)(w.x >> 24));
            us[4] = f2bf((float)(w.y & 0xffu));
            us[5] = f2bf((float)((w.y >> 8) & 0xffu));
            us[6] = f2bf((float)((w.y >> 16) & 0xffu));
            us[7] = f2bf((float)(w.y >> 24));
            *(uint4*)(&As[row * PADK + ko]) = *(uint4*)us;
        }
        __syncthreads();
        // issue ALL of this chunk's B loads first (8x 16B, independent);
        // the A ds_reads + early MFMAs below hide their L2 latency.
        short8 bh[2][2], bl[2][2];               // [ks][nt]
        #pragma unroll
        for (int ks = 0; ks < 2; ks++) {
            int kb = kc + ks * 32 + quad * 8;
            #pragma unroll
            for (int nt = 0; nt < 2; nt++) {
                bh[ks][nt] = *(const short8*)(bp_h[nt] + kb);
                bl[ks][nt] = *(const short8*)(bp_l[nt] + kb);
            }
        }
        #pragma unroll
        for (int ks = 0; ks < 2; ks++) {
            int kb = ks * 32 + quad * 8;
            short8 a[8];
            #pragma unroll
            for (int mt = 0; mt < 8; mt++)
                a[mt] = *(const short8*)(&As[(mt * 16 + l15) * PADK + kb]);
            #pragma unroll
            for (int nt = 0; nt < 2; nt++) {
                #pragma unroll
                for (int mt = 0; mt < 8; mt++) {
                    acc[mt * 2 + nt] = __builtin_amdgcn_mfma_f32_16x16x32_bf16(a[mt], bh[ks][nt], acc[mt * 2 + nt], 0, 0, 0);
                    acc[mt * 2 + nt] = __builtin_amdgcn_mfma_f32_16x16x32_bf16(a[mt], bl[ks][nt], acc[mt * 2 + nt], 0, 0, 0);
                }
            }
        }
    }
    // epilogue: C/D col=l15 -> feat, row=quad*4+rg -> dst-local (verified R7/R8)
    int gbase = g * 512 + mb;
    int fA = wv * 32 + l15;
    float bf0 = bias[fA], bf1 = bias[fA + 16];
    float cs[2] = {0.f, 0.f}, cq[2] = {0.f, 0.f};
    #pragma unroll
    for (int mt = 0; mt < 8; mt++) {
        int n0 = gbase + mt * 16 + quad * 4;
        float4 dv = *(const float4*)(dinv + n0);
        #pragma unroll
        for (int nt = 0; nt < 2; nt++) {
            int f = fA + nt * 16;
            float bf = nt ? bf1 : bf0;
            float4v a = acc[mt * 2 + nt];
            float v0 = fmaf(dv.x, a[0], bf);
            float v1 = fmaf(dv.y, a[1], bf);
            float v2 = fmaf(dv.z, a[2], bf);
            float v3 = fmaf(dv.w, a[3], bf);
            pre[(size_t)(n0 + 0) * 128 + f] = v0;
            pre[(size_t)(n0 + 1) * 128 + f] = v1;
            pre[(size_t)(n0 + 2) * 128 + f] = v2;
            pre[(size_t)(n0 + 3) * 128 + f] = v3;
            cs[nt] += v0 + v1 + v2 + v3;
            cq[nt] = fmaf(v0, v0, cq[nt]); cq[nt] = fmaf(v1, v1, cq[nt]);
            cq[nt] = fmaf(v2, v2, cq[nt]); cq[nt] = fmaf(v3, v3, cq[nt]);
        }
    }
    #pragma unroll
    for (int nt = 0; nt < 2; nt++) {
        float cs_ = cs[nt], cq_ = cq[nt];
        cs_ += __shfl_xor(cs_, 16); cs_ += __shfl_xor(cs_, 32);
        cq_ += __shfl_xor(cq_, 16); cq_ += __shfl_xor(cq_, 32);
        if (quad == 0) {
            atomicAdd(&stats[fA + nt * 16], cs_);
            atomicAdd(&stats[128 + fA + nt * 16], cq_);
        }
    }
}

// ---------------- feature matmul: hwT_next = dinv ⊙ (relu(bn(pre)) @ W)^T --
// Exact R13 version: C = Wt @ X^T, M=128 f', N=64 nodes, K=128 (BK=64 chunks),
// split-precision 3-pass, LDS-staged W (X has real cross-wave reuse here).
__global__ __launch_bounds__(256) void k_mmT(const float* __restrict__ pre,
        const float* __restrict__ stats, const float* __restrict__ gamma,
        const float* __restrict__ beta, const float* __restrict__ dinv,
        const unsigned short* __restrict__ Wt_h, const unsigned short* __restrict__ Wt_l,
        unsigned short* __restrict__ hwT_h, unsigned short* __restrict__ hwT_l) {
    __shared__ unsigned short Ws_h[128 * PADK], Ws_l[128 * PADK];  // 36.9KB
    __shared__ unsigned short Xs_h[64 * PADK], Xs_l[64 * PADK];    // 18.4KB
    __shared__ float scL[256];
    int t = threadIdx.x, lane = t & 63, wv = t >> 6;
    int l15 = lane & 15, quad = lane >> 4;
    int b = blockIdx.x, r = b & 7, q = b >> 3;
    int g = r + 8 * (q & 7);
    int nb = g * NPGC + (q >> 3) * 64;
    if (t < 128) {
        float mu = stats[t] * (1.0f / NN);
        float var = stats[128 + t] * (1.0f / NN) - mu * mu;
        float s = gamma[t] * rsqrtf(var + EPSF);
        scL[t] = s;
        scL[128 + t] = fmaf(-mu, s, beta[t]);
    }
    float4v acc[8];
    #pragma unroll
    for (int i = 0; i < 8; i++) acc[i] = (float4v)0.f;

    for (int kc = 0; kc < 128; kc += 64) {
        __syncthreads();    // first iter: publishes scL
        #pragma unroll
        for (int i = 0; i < 4; i++) {            // Wt planes: 1024 units each
            int u = t + i * 256;
            int fp = u >> 3, ko = (u & 7) * 8;
            int go = fp * 128 + kc + ko;
            *(uint4*)(&Ws_h[fp * PADK + ko]) = *(const uint4*)(Wt_h + go);
            *(uint4*)(&Ws_l[fp * PADK + ko]) = *(const uint4*)(Wt_l + go);
        }
        #pragma unroll
        for (int i = 0; i < 2; i++) {            // X: 512 units, bn+relu+split
            int u = t + i * 256;
            int n = u >> 3, fo = (u & 7) * 8;
            const float* pp = pre + (size_t)(nb + n) * 128 + kc + fo;
            float4 v0 = *(const float4*)(pp);
            float4 v1 = *(const float4*)(pp + 4);
            float4 s0 = *(const float4*)(&scL[kc + fo]);
            float4 s1 = *(const float4*)(&scL[kc + fo + 4]);
            float4 h0 = *(const float4*)(&scL[128 + kc + fo]);
            float4 h1 = *(const float4*)(&scL[128 + kc + fo + 4]);
            float v[8] = {fmaxf(fmaf(v0.x, s0.x, h0.x), 0.f),
                          fmaxf(fmaf(v0.y, s0.y, h0.y), 0.f),
                          fmaxf(fmaf(v0.z, s0.z, h0.z), 0.f),
                          fmaxf(fmaf(v0.w, s0.w, h0.w), 0.f),
                          fmaxf(fmaf(v1.x, s1.x, h1.x), 0.f),
                          fmaxf(fmaf(v1.y, s1.y, h1.y), 0.f),
                          fmaxf(fmaf(v1.z, s1.z, h1.z), 0.f),
                          fmaxf(fmaf(v1.w, s1.w, h1.w), 0.f)};
            unsigned short uh[8], ul[8];
            #pragma unroll
            for (int j = 0; j < 8; j++) splitbf(v[j], uh[j], ul[j]);
            *(uint4*)(&Xs_h[n * PADK + fo]) = *(uint4*)uh;
            *(uint4*)(&Xs_l[n * PADK + fo]) = *(uint4*)ul;
        }
        __syncthreads();
        int m0 = wv * 32;
        #pragma unroll
        for (int ks = 0; ks < 2; ks++) {
            int kb = ks * 32 + quad * 8;
            short8 a0h = *(const short8*)(&Ws_h[(m0 + l15) * PADK + kb]);
            short8 a0l = *(const short8*)(&Ws_l[(m0 + l15) * PADK + kb]);
            short8 a1h = *(const short8*)(&Ws_h[(m0 + 16 + l15) * PADK + kb]);
            short8 a1l = *(const short8*)(&Ws_l[(m0 + 16 + l15) * PADK + kb]);
            #pragma unroll
            for (int nt = 0; nt < 4; nt++) {
                short8 bh = *(const short8*)(&Xs_h[(nt * 16 + l15) * PADK + kb]);
                short8 bl = *(const short8*)(&Xs_l[(nt * 16 + l15) * PADK + kb]);
                acc[nt]     = __builtin_amdgcn_mfma_f32_16x16x32_bf16(a0h, bh, acc[nt], 0, 0, 0);
                acc[nt]     = __builtin_amdgcn_mfma_f32_16x16x32_bf16(a0h, bl, acc[nt], 0, 0, 0);
                acc[nt]     = __builtin_amdgcn_mfma_f32_16x16x32_bf16(a0l, bh, acc[nt], 0, 0, 0);
                acc[4 + nt] = __builtin_amdgcn_mfma_f32_16x16x32_bf16(a1h, bh, acc[4 + nt], 0, 0, 0);
                acc[4 + nt] = __builtin_amdgcn_mfma_f32_16x16x32_bf16(a1h, bl, acc[4 + nt], 0, 0, 0);
                acc[4 + nt] = __builtin_amdgcn_mfma_f32_16x16x32_bf16(a1l, bh, acc[4 + nt], 0, 0, 0);
            }
        }
    }
    #pragma unroll
    for (int mt = 0; mt < 2; mt++) {
        #pragma unroll
        for (int nt = 0; nt < 4; nt++) {
            int n = nb + nt * 16 + l15;
            float dv = dinv[n];
            int fp0 = wv * 32 + mt * 16 + quad * 4;
            float4v a = acc[mt * 4 + nt];
            #pragma unroll
            for (int rg = 0; rg < 4; rg++) {
                unsigned short h, lo;
                splitbf(dv * a[rg], h, lo);
                hwT_h[(size_t)(fp0 + rg) * NN + n] = h;
                hwT_l[(size_t)(fp0 + rg) * NN + n] = lo;
            }
        }
    }
}

// last layer: BN+ReLU in-place + per-graph column sums. 512 blocks, swizzled.
__global__ __launch_bounds__(256) void k_bn_pool(float* __restrict__ pre,
        const float* __restrict__ stats, const float* __restrict__ gamma,
        const float* __restrict__ beta, float* __restrict__ meansum) {
    __shared__ float ssum[256];
    __shared__ float scL[256];
    int t = threadIdx.x;
    int b = blockIdx.x, r = b & 7, q = b >> 3;
    int g = r + 8 * (q & 7);
    int nb = g * NPGC + (q >> 3) * 64;
    if (t < 128) {
        float mu = stats[t] * (1.0f / NN);
        float var = stats[128 + t] * (1.0f / NN) - mu * mu;
        float s = gamma[t] * rsqrtf(var + EPSF);
        scL[t] = s;
        scL[128 + t] = fmaf(-mu, s, beta[t]);
    }
    __syncthreads();
    int f = t & 127;
    float s = scL[f], sh = scL[128 + f];
    float lsum = 0.f;
    int base = nb * 128;
    for (int i = 0; i < 32; i++) {
        int idx = base + i * 256 + t;
        float v = fmaxf(fmaf(pre[idx], s, sh), 0.f);
        pre[idx] = v;
        lsum += v;
    }
    ssum[t] = lsum;
    __syncthreads();
    if (t < 128) atomicAdd(&meansum[g * 128 + f], ssum[t] + ssum[t + 128]);
}

// tg = tanh((meansum/512) @ W_att), per graph
__global__ void k_tg(const float* __restrict__ meansum, const float* __restrict__ Watt,
                     float* __restrict__ tg) {
    __shared__ float m[128];
    int g = blockIdx.x, t = threadIdx.x;  // 128 threads
    m[t] = meansum[g * 128 + t] * (1.0f / NPGC);
    __syncthreads();
    float a2 = 0.f;
    for (int k = 0; k < 128; k++) a2 = fmaf(m[k], Watt[k * 128 + t], a2);
    tg[g * 128 + t] = tanhf(a2);
}

// coefs = sigmoid(10*<h,tg>) and gf += coef*h. 512 blocks, swizzled.
__global__ __launch_bounds__(256) void k_coef_gf(const float* __restrict__ h,
        const float* __restrict__ tg, float* __restrict__ gf) {
    __shared__ float tgs[128];
    __shared__ float coef[64];
    int t = threadIdx.x;
    int b = blockIdx.x, r = b & 7, q = b >> 3;
    int g = r + 8 * (q & 7);
    int n0 = (q >> 3) * 64;
    if (t < 128) tgs[t] = tg[g * 128 + t];
    __syncthreads();
    int wid = t >> 6, lane = t & 63;
    const float* hp = h + (size_t)g * NPGC * 128;
    for (int j = wid; j < 64; j += 4) {
        int n = n0 + j;
        float p = hp[n * 128 + lane] * tgs[lane] + hp[n * 128 + 64 + lane] * tgs[64 + lane];
        for (int off = 32; off; off >>= 1) p += __shfl_xor(p, off);
        if (lane == 0) coef[j] = 1.0f / (1.0f + expf(-10.0f * p));
    }
    __syncthreads();
    int f = t & 127, half = t >> 7;
    float acc = 0.f;
    for (int j = 0; j < 32; j++) {
        int jj = half * 32 + j;
        acc = fmaf(coef[jj], hp[(n0 + jj) * 128 + f], acc);
    }
    atomicAdd(&gf[g * 128 + f], acc);
}

// output writer
__global__ void k_out(const float* __restrict__ h, const float* __restrict__ gf,
                      float* __restrict__ out) {
    int idx = blockIdx.x * 256 + threadIdx.x;
    int c4 = (idx & 63) * 4;
    int n = idx >> 6;
    int g = n >> 9;
    float4 v = (c4 < 128) ? *(const float4*)(h + (size_t)n * 128 + c4)
                          : *(const float4*)(gf + g * 128 + (c4 - 128));
    *(float4*)(out + (size_t)idx * 4) = v;
}

// ---------------- host ----------------
extern "C" void kernel_launch(void* const* d_in, const int* in_sizes, int n_in,
                              void* d_out, int out_size, void* d_ws, size_t ws_size,
                              hipStream_t stream) {
    const float* x     = (const float*)d_in[0];
    const int*   esrc  = (const int*)d_in[1];
    const int*   edst  = (const int*)d_in[2];
    const float* W0    = (const float*)d_in[4];
    const float* b0    = (const float*)d_in[5];
    const float* Wr    = (const float*)d_in[6];
    const float* br    = (const float*)d_in[7];
    const float* gamma = (const float*)d_in[8];
    const float* beta  = (const float*)d_in[9];
    const float* Watt  = (const float*)d_in[10];
    float* out = (float*)d_out;
    float* ws  = (float*)d_ws;

    // workspace layout (float units), ~51MB
    int*   cnt     = (int*)(ws + 0);             // 32768
    float* dinv    = ws + 32768;                 // 32768
    float* stats   = ws + 65536;                 // 2560
    float* tgbuf   = ws + 68096;                 // 8192
    float* meansum = ws + 76288;                 // 8192
    float* gf      = ws + 84480;                 // 8192
    unsigned short* Wt_h  = (unsigned short*)(ws + 92672);     // 147456 sh
    unsigned short* Wt_l  = (unsigned short*)(ws + 166400);
    unsigned short* hwT_h = (unsigned short*)(ws + 240128);    // 4.19M sh
    unsigned short* hwT_l = (unsigned short*)(ws + 2337280);
    unsigned char*  Mu8   = (unsigned char*)(ws + 4434432);    // NN*512 u8 = 16.7MB
    float* pre     = ws + 8628736;               // NN*128 fp32
    // end: 12823040 floats = 51.3MB

    hipMemsetAsync(cnt, 0, NN * sizeof(int), stream);
    hipMemsetAsync(stats, 0, LL * 256 * sizeof(float), stream);
    hipMemsetAsync(meansum, 0, BG * 128 * sizeof(float), stream);
    hipMemsetAsync(gf, 0, BG * 128 * sizeof(float), stream);
    hipMemsetAsync(Mu8, 0, (size_t)NN * 512, stream);

    k_histM<<<EE / 256, 256, 0, stream>>>(esrc, edst, (unsigned int*)Mu8, cnt);
    k_diag<<<NN / 256, 256, 0, stream>>>(Mu8);
    k_dinv<<<NN / 256, 256, 0, stream>>>(cnt, dinv);
    k_wt<<<9 * 16384 / 256, 256, 0, stream>>>(Wr, Wt_h, Wt_l);
    k_l0<<<128 * (NN / 8) / 256, 256, 0, stream>>>(x, W0, dinv, hwT_h, hwT_l);

    for (int l = 0; l < LL; l++) {
        const float* bias = (l == 0) ? b0 : br + (l - 1) * DD;
        k_aggmm<<<NN / 128, 256, 0, stream>>>(Mu8, hwT_h, hwT_l, dinv, bias,
                                              pre, stats + l * 256);
        if (l < LL - 1)
            k_mmT<<<NN / 64, 256, 0, stream>>>(pre, stats + l * 256, gamma + l * DD,
                                               beta + l * DD, dinv, Wt_h + l * 16384,
                                               Wt_l + l * 16384, hwT_h, hwT_l);
        else
            k_bn_pool<<<NN / 64, 256, 0, stream>>>(pre, stats + l * 256, gamma + l * DD,
                                                   beta + l * DD, meansum);
    }
    k_tg<<<BG, 128, 0, stream>>>(meansum, Watt, tgbuf);
    k_coef_gf<<<NN / 64, 256, 0, stream>>>(pre, tgbuf, gf);
    k_out<<<NN * 64 / 256, 256, 0, stream>>>(pre, gf, out);
}

// Round 15
// 498.841 us; speedup vs baseline: 1.0489x; 1.0489x over previous
//
#include <hip/hip_runtime.h>
#include <hip/hip_bf16.h>
#include <math.h>

#define NN 32768      // B*NPG nodes
#define BG 64         // graphs
#define NPGC 512      // nodes per graph
#define DD 128        // hidden dim
#define EE 524288     // edges
#define LL 10         // layers
#define EPSF 1e-5f
#define PADK 72       // LDS pitch (halfwords): 2-way bank aliasing only (free, m136)

typedef __attribute__((ext_vector_type(8))) short short8;
typedef __attribute__((ext_vector_type(4))) float float4v;

static __device__ __forceinline__ unsigned short f2bf(float x) {
    __hip_bfloat16 b = __float2bfloat16(x);
    return *reinterpret_cast<unsigned short*>(&b);
}
static __device__ __forceinline__ float bf2f(unsigned short u) {
    unsigned int v = ((unsigned int)u) << 16;
    return __uint_as_float(v);
}
// split x into hi+lo bf16 (residual <= 2^-18 |x|)
static __device__ __forceinline__ void splitbf(float x, unsigned short& h, unsigned short& l) {
    unsigned short hh = f2bf(x);
    h = hh;
    l = f2bf(x - bf2f(hh));
}

// R15 = exact revert to R13 (501.2us best). R14's B-direct-from-global
// regressed: LDS staging of B is also latency aggregation (burst-coalesced
// wave-wide loads), not just a reuse cache. Structure notes:
// - XCD swizzle (confirmed R4): graph g on blocks with blockIdx%8 == g%8.
// - Adj = diag(dinv) M diag(dinv); M = A+I small-int stored u8 (exact),
//   expanded to bf16 in VALU during staging (R13: FETCH 27.9->16.5MB).
// - Split-precision bf16 hi/lo everywhere else: 2-pass aggregation (M exact),
//   3-pass feature matmul. absmax 4.0 == fp32 path.

// ---------------- prologue ----------------
// byte-packed histogram directly into Mu8 (4 cells per u32 atomic)
__global__ void k_histM(const int* __restrict__ src, const int* __restrict__ dst,
                        unsigned int* __restrict__ Mp, int* __restrict__ cnt) {
    int e = blockIdx.x * 256 + threadIdx.x;
    int d = dst[e], s = src[e] & 511;
    int cell = (d << 9) + s;
    atomicAdd(&Mp[cell >> 2], 1u << ((cell & 3) << 3));
    atomicAdd(&cnt[d], 1);
}

// +1 on each node's local diagonal, in place (runs after k_histM)
__global__ void k_diag(unsigned char* __restrict__ Mu8) {
    int n = blockIdx.x * 256 + threadIdx.x;
    Mu8[(size_t)n * 512 + (n & 511)] += 1;
}

__global__ void k_dinv(const int* __restrict__ cnt, float* __restrict__ dinv) {
    int n = blockIdx.x * 256 + threadIdx.x;
    dinv[n] = rsqrtf(1.0f + (float)cnt[n]);
}

// Wt[l][f'][f] = split(W_rest[l][f][f'])
__global__ void k_wt(const float* __restrict__ Wr, unsigned short* __restrict__ Wt_h,
                     unsigned short* __restrict__ Wt_l) {
    int idx = blockIdx.x * 256 + threadIdx.x;   // over 9*16384
    int l = idx >> 14, rem = idx & 16383;
    int fp = rem >> 7, f = rem & 127;
    unsigned short h, lo;
    splitbf(Wr[l * 16384 + f * 128 + fp], h, lo);
    Wt_h[idx] = h;
    Wt_l[idx] = lo;
}

// layer-0: hwT[f][n] = split(dinv[n] * x[n] * W0[f])
__global__ void k_l0(const float* __restrict__ x, const float* __restrict__ W0,
                     const float* __restrict__ dinv,
                     unsigned short* __restrict__ hwT_h, unsigned short* __restrict__ hwT_l) {
    int u = blockIdx.x * 256 + threadIdx.x;     // 128*4096 units of 8 nodes
    int f = u >> 12, n0 = (u & 4095) * 8;
    float w = W0[f];
    float4 xa = *(const float4*)(x + n0);
    float4 xb = *(const float4*)(x + n0 + 4);
    float4 da = *(const float4*)(dinv + n0);
    float4 db = *(const float4*)(dinv + n0 + 4);
    float v[8] = {xa.x * w * da.x, xa.y * w * da.y, xa.z * w * da.z, xa.w * w * da.w,
                  xb.x * w * db.x, xb.y * w * db.y, xb.z * w * db.z, xb.w * w * db.w};
    unsigned short uh[8], ul[8];
    #pragma unroll
    for (int i = 0; i < 8; i++) splitbf(v[i], uh[i], ul[i]);
    *(uint4*)(hwT_h + (size_t)f * NN + n0) = *(uint4*)uh;
    *(uint4*)(hwT_l + (size_t)f * NN + n0) = *(uint4*)ul;
}

// ---------------- aggregation: pre = diag(dinv) (M @ hwT^T) + bias ---------
// 256 blocks (4/graph, XCD-swizzled), 256 threads, 128 dst x 128 f, K=512,
// BK=64. A-operand u8 in memory, expanded to bf16 in registers during staging
// (VALU pipe, overlaps MFMA per m114). B planes LDS-staged (burst-coalesced).
__global__ __launch_bounds__(256) void k_aggmm(const unsigned char* __restrict__ Mu8,
        const unsigned short* __restrict__ hwT_h, const unsigned short* __restrict__ hwT_l,
        const float* __restrict__ dinv, const float* __restrict__ bias,
        float* __restrict__ pre, float* __restrict__ stats) {
    __shared__ unsigned short As[128 * PADK];                      // 18.4KB
    __shared__ unsigned short Bs_h[128 * PADK], Bs_l[128 * PADK];  // 36.9KB
    int t = threadIdx.x, lane = t & 63, wv = t >> 6;
    int l15 = lane & 15, quad = lane >> 4;
    int b = blockIdx.x, r = b & 7, q = b >> 3;   // q: 0..31
    int g = r + 8 * (q & 7);
    int mb = (q >> 3) * 128;                     // 4 tiles of 128 dst per graph
    size_t arow = ((size_t)g * 512 + mb) * 512;  // byte offset into Mu8
    size_t gcol = (size_t)g * 512;
    float4v acc[16];         // [mt 0..7][nt 0..1]
    #pragma unroll
    for (int i = 0; i < 16; i++) acc[i] = (float4v)0.f;

    for (int kc = 0; kc < 512; kc += 64) {
        __syncthreads();
        #pragma unroll
        for (int i = 0; i < 4; i++) {            // A: 1024 units of 8 u8 cells
            int u = t + i * 256;
            int row = u >> 3, ko = (u & 7) * 8;
            uint2 w = *(const uint2*)(Mu8 + arow + (size_t)row * 512 + kc + ko);
            unsigned short us[8];
            us[0] = f2bf((float)(w.x & 0xffu));
            us[1] = f2bf((float)((w.x >> 8) & 0xffu));
            us[2] = f2bf((float)((w.x >> 16) & 0xffu));
            us[3] = f2bf((float)(w.x >> 24));
            us[4] = f2bf((float)(w.y & 0xffu));
            us[5] = f2bf((float)((w.y >> 8) & 0xffu));
            us[6] = f2bf((float)((w.y >> 16) & 0xffu));
            us[7] = f2bf((float)(w.y >> 24));
            *(uint4*)(&As[row * PADK + ko]) = *(uint4*)us;
        }
        #pragma unroll
        for (int i = 0; i < 4; i++) {            // B planes: 1024 units each
            int u = t + i * 256;
            int f = u >> 3, ko = (u & 7) * 8;
            size_t go = (size_t)f * NN + gcol + kc + ko;
            *(uint4*)(&Bs_h[f * PADK + ko]) = *(const uint4*)(hwT_h + go);
            *(uint4*)(&Bs_l[f * PADK + ko]) = *(const uint4*)(hwT_l + go);
        }
        __syncthreads();
        int f0 = wv * 32;
        #pragma unroll
        for (int ks = 0; ks < 2; ks++) {
            int kb = ks * 32 + quad * 8;
            short8 a[8];
            #pragma unroll
            for (int mt = 0; mt < 8; mt++)
                a[mt] = *(const short8*)(&As[(mt * 16 + l15) * PADK + kb]);
            #pragma unroll
            for (int nt = 0; nt < 2; nt++) {
                short8 bh = *(const short8*)(&Bs_h[(f0 + nt * 16 + l15) * PADK + kb]);
                short8 bl = *(const short8*)(&Bs_l[(f0 + nt * 16 + l15) * PADK + kb]);
                #pragma unroll
                for (int mt = 0; mt < 8; mt++) {
                    acc[mt * 2 + nt] = __builtin_amdgcn_mfma_f32_16x16x32_bf16(a[mt], bh, acc[mt * 2 + nt], 0, 0, 0);
                    acc[mt * 2 + nt] = __builtin_amdgcn_mfma_f32_16x16x32_bf16(a[mt], bl, acc[mt * 2 + nt], 0, 0, 0);
                }
            }
        }
    }
    // epilogue: C/D col=l15 -> feat, row=quad*4+rg -> dst-local (verified R7/R8)
    int gbase = g * 512 + mb;
    int fA = wv * 32 + l15;
    float bf0 = bias[fA], bf1 = bias[fA + 16];
    float cs[2] = {0.f, 0.f}, cq[2] = {0.f, 0.f};
    #pragma unroll
    for (int mt = 0; mt < 8; mt++) {
        int n0 = gbase + mt * 16 + quad * 4;
        float4 dv = *(const float4*)(dinv + n0);
        #pragma unroll
        for (int nt = 0; nt < 2; nt++) {
            int f = fA + nt * 16;
            float bf = nt ? bf1 : bf0;
            float4v a = acc[mt * 2 + nt];
            float v0 = fmaf(dv.x, a[0], bf);
            float v1 = fmaf(dv.y, a[1], bf);
            float v2 = fmaf(dv.z, a[2], bf);
            float v3 = fmaf(dv.w, a[3], bf);
            pre[(size_t)(n0 + 0) * 128 + f] = v0;
            pre[(size_t)(n0 + 1) * 128 + f] = v1;
            pre[(size_t)(n0 + 2) * 128 + f] = v2;
            pre[(size_t)(n0 + 3) * 128 + f] = v3;
            cs[nt] += v0 + v1 + v2 + v3;
            cq[nt] = fmaf(v0, v0, cq[nt]); cq[nt] = fmaf(v1, v1, cq[nt]);
            cq[nt] = fmaf(v2, v2, cq[nt]); cq[nt] = fmaf(v3, v3, cq[nt]);
        }
    }
    #pragma unroll
    for (int nt = 0; nt < 2; nt++) {
        float cs_ = cs[nt], cq_ = cq[nt];
        cs_ += __shfl_xor(cs_, 16); cs_ += __shfl_xor(cs_, 32);
        cq_ += __shfl_xor(cq_, 16); cq_ += __shfl_xor(cq_, 32);
        if (quad == 0) {
            atomicAdd(&stats[fA + nt * 16], cs_);
            atomicAdd(&stats[128 + fA + nt * 16], cq_);
        }
    }
}

// ---------------- feature matmul: hwT_next = dinv ⊙ (relu(bn(pre)) @ W)^T --
// C = Wt @ X^T, M=128 f', N=64 nodes, K=128 (BK=64 chunks), split-precision
// 3-pass, LDS-staged W + X (X has real cross-wave reuse).
__global__ __launch_bounds__(256) void k_mmT(const float* __restrict__ pre,
        const float* __restrict__ stats, const float* __restrict__ gamma,
        const float* __restrict__ beta, const float* __restrict__ dinv,
        const unsigned short* __restrict__ Wt_h, const unsigned short* __restrict__ Wt_l,
        unsigned short* __restrict__ hwT_h, unsigned short* __restrict__ hwT_l) {
    __shared__ unsigned short Ws_h[128 * PADK], Ws_l[128 * PADK];  // 36.9KB
    __shared__ unsigned short Xs_h[64 * PADK], Xs_l[64 * PADK];    // 18.4KB
    __shared__ float scL[256];
    int t = threadIdx.x, lane = t & 63, wv = t >> 6;
    int l15 = lane & 15, quad = lane >> 4;
    int b = blockIdx.x, r = b & 7, q = b >> 3;
    int g = r + 8 * (q & 7);
    int nb = g * NPGC + (q >> 3) * 64;
    if (t < 128) {
        float mu = stats[t] * (1.0f / NN);
        float var = stats[128 + t] * (1.0f / NN) - mu * mu;
        float s = gamma[t] * rsqrtf(var + EPSF);
        scL[t] = s;
        scL[128 + t] = fmaf(-mu, s, beta[t]);
    }
    float4v acc[8];
    #pragma unroll
    for (int i = 0; i < 8; i++) acc[i] = (float4v)0.f;

    for (int kc = 0; kc < 128; kc += 64) {
        __syncthreads();    // first iter: publishes scL
        #pragma unroll
        for (int i = 0; i < 4; i++) {            // Wt planes: 1024 units each
            int u = t + i * 256;
            int fp = u >> 3, ko = (u & 7) * 8;
            int go = fp * 128 + kc + ko;
            *(uint4*)(&Ws_h[fp * PADK + ko]) = *(const uint4*)(Wt_h + go);
            *(uint4*)(&Ws_l[fp * PADK + ko]) = *(const uint4*)(Wt_l + go);
        }
        #pragma unroll
        for (int i = 0; i < 2; i++) {            // X: 512 units, bn+relu+split
            int u = t + i * 256;
            int n = u >> 3, fo = (u & 7) * 8;
            const float* pp = pre + (size_t)(nb + n) * 128 + kc + fo;
            float4 v0 = *(const float4*)(pp);
            float4 v1 = *(const float4*)(pp + 4);
            float4 s0 = *(const float4*)(&scL[kc + fo]);
            float4 s1 = *(const float4*)(&scL[kc + fo + 4]);
            float4 h0 = *(const float4*)(&scL[128 + kc + fo]);
            float4 h1 = *(const float4*)(&scL[128 + kc + fo + 4]);
            float v[8] = {fmaxf(fmaf(v0.x, s0.x, h0.x), 0.f),
                          fmaxf(fmaf(v0.y, s0.y, h0.y), 0.f),
                          fmaxf(fmaf(v0.z, s0.z, h0.z), 0.f),
                          fmaxf(fmaf(v0.w, s0.w, h0.w), 0.f),
                          fmaxf(fmaf(v1.x, s1.x, h1.x), 0.f),
                          fmaxf(fmaf(v1.y, s1.y, h1.y), 0.f),
                          fmaxf(fmaf(v1.z, s1.z, h1.z), 0.f),
                          fmaxf(fmaf(v1.w, s1.w, h1.w), 0.f)};
            unsigned short uh[8], ul[8];
            #pragma unroll
            for (int j = 0; j < 8; j++) splitbf(v[j], uh[j], ul[j]);
            *(uint4*)(&Xs_h[n * PADK + fo]) = *(uint4*)uh;
            *(uint4*)(&Xs_l[n * PADK + fo]) = *(uint4*)ul;
        }
        __syncthreads();
        int m0 = wv * 32;
        #pragma unroll
        for (int ks = 0; ks < 2; ks++) {
            int kb = ks * 32 + quad * 8;
            short8 a0h = *(const short8*)(&Ws_h[(m0 + l15) * PADK + kb]);
            short8 a0l = *(const short8*)(&Ws_l[(m0 + l15) * PADK + kb]);
            short8 a1h = *(const short8*)(&Ws_h[(m0 + 16 + l15) * PADK + kb]);
            short8 a1l = *(const short8*)(&Ws_l[(m0 + 16 + l15) * PADK + kb]);
            #pragma unroll
            for (int nt = 0; nt < 4; nt++) {
                short8 bh = *(const short8*)(&Xs_h[(nt * 16 + l15) * PADK + kb]);
                short8 bl = *(const short8*)(&Xs_l[(nt * 16 + l15) * PADK + kb]);
                acc[nt]     = __builtin_amdgcn_mfma_f32_16x16x32_bf16(a0h, bh, acc[nt], 0, 0, 0);
                acc[nt]     = __builtin_amdgcn_mfma_f32_16x16x32_bf16(a0h, bl, acc[nt], 0, 0, 0);
                acc[nt]     = __builtin_amdgcn_mfma_f32_16x16x32_bf16(a0l, bh, acc[nt], 0, 0, 0);
                acc[4 + nt] = __builtin_amdgcn_mfma_f32_16x16x32_bf16(a1h, bh, acc[4 + nt], 0, 0, 0);
                acc[4 + nt] = __builtin_amdgcn_mfma_f32_16x16x32_bf16(a1h, bl, acc[4 + nt], 0, 0, 0);
                acc[4 + nt] = __builtin_amdgcn_mfma_f32_16x16x32_bf16(a1l, bh, acc[4 + nt], 0, 0, 0);
            }
        }
    }
    #pragma unroll
    for (int mt = 0; mt < 2; mt++) {
        #pragma unroll
        for (int nt = 0; nt < 4; nt++) {
            int n = nb + nt * 16 + l15;
            float dv = dinv[n];
            int fp0 = wv * 32 + mt * 16 + quad * 4;
            float4v a = acc[mt * 4 + nt];
            #pragma unroll
            for (int rg = 0; rg < 4; rg++) {
                unsigned short h, lo;
                splitbf(dv * a[rg], h, lo);
                hwT_h[(size_t)(fp0 + rg) * NN + n] = h;
                hwT_l[(size_t)(fp0 + rg) * NN + n] = lo;
            }
        }
    }
}

// last layer: BN+ReLU in-place + per-graph column sums. 512 blocks, swizzled.
__global__ __launch_bounds__(256) void k_bn_pool(float* __restrict__ pre,
        const float* __restrict__ stats, const float* __restrict__ gamma,
        const float* __restrict__ beta, float* __restrict__ meansum) {
    __shared__ float ssum[256];
    __shared__ float scL[256];
    int t = threadIdx.x;
    int b = blockIdx.x, r = b & 7, q = b >> 3;
    int g = r + 8 * (q & 7);
    int nb = g * NPGC + (q >> 3) * 64;
    if (t < 128) {
        float mu = stats[t] * (1.0f / NN);
        float var = stats[128 + t] * (1.0f / NN) - mu * mu;
        float s = gamma[t] * rsqrtf(var + EPSF);
        scL[t] = s;
        scL[128 + t] = fmaf(-mu, s, beta[t]);
    }
    __syncthreads();
    int f = t & 127;
    float s = scL[f], sh = scL[128 + f];
    float lsum = 0.f;
    int base = nb * 128;
    for (int i = 0; i < 32; i++) {
        int idx = base + i * 256 + t;
        float v = fmaxf(fmaf(pre[idx], s, sh), 0.f);
        pre[idx] = v;
        lsum += v;
    }
    ssum[t] = lsum;
    __syncthreads();
    if (t < 128) atomicAdd(&meansum[g * 128 + f], ssum[t] + ssum[t + 128]);
}

// tg = tanh((meansum/512) @ W_att), per graph
__global__ void k_tg(const float* __restrict__ meansum, const float* __restrict__ Watt,
                     float* __restrict__ tg) {
    __shared__ float m[128];
    int g = blockIdx.x, t = threadIdx.x;  // 128 threads
    m[t] = meansum[g * 128 + t] * (1.0f / NPGC);
    __syncthreads();
    float a2 = 0.f;
    for (int k = 0; k < 128; k++) a2 = fmaf(m[k], Watt[k * 128 + t], a2);
    tg[g * 128 + t] = tanhf(a2);
}

// coefs = sigmoid(10*<h,tg>) and gf += coef*h. 512 blocks, swizzled.
__global__ __launch_bounds__(256) void k_coef_gf(const float* __restrict__ h,
        const float* __restrict__ tg, float* __restrict__ gf) {
    __shared__ float tgs[128];
    __shared__ float coef[64];
    int t = threadIdx.x;
    int b = blockIdx.x, r = b & 7, q = b >> 3;
    int g = r + 8 * (q & 7);
    int n0 = (q >> 3) * 64;
    if (t < 128) tgs[t] = tg[g * 128 + t];
    __syncthreads();
    int wid = t >> 6, lane = t & 63;
    const float* hp = h + (size_t)g * NPGC * 128;
    for (int j = wid; j < 64; j += 4) {
        int n = n0 + j;
        float p = hp[n * 128 + lane] * tgs[lane] + hp[n * 128 + 64 + lane] * tgs[64 + lane];
        for (int off = 32; off; off >>= 1) p += __shfl_xor(p, off);
        if (lane == 0) coef[j] = 1.0f / (1.0f + expf(-10.0f * p));
    }
    __syncthreads();
    int f = t & 127, half = t >> 7;
    float acc = 0.f;
    for (int j = 0; j < 32; j++) {
        int jj = half * 32 + j;
        acc = fmaf(coef[jj], hp[(n0 + jj) * 128 + f], acc);
    }
    atomicAdd(&gf[g * 128 + f], acc);
}

// output writer
__global__ void k_out(const float* __restrict__ h, const float* __restrict__ gf,
                      float* __restrict__ out) {
    int idx = blockIdx.x * 256 + threadIdx.x;
    int c4 = (idx & 63) * 4;
    int n = idx >> 6;
    int g = n >> 9;
    float4 v = (c4 < 128) ? *(const float4*)(h + (size_t)n * 128 + c4)
                          : *(const float4*)(gf + g * 128 + (c4 - 128));
    *(float4*)(out + (size_t)idx * 4) = v;
}

// ---------------- host ----------------
extern "C" void kernel_launch(void* const* d_in, const int* in_sizes, int n_in,
                              void* d_out, int out_size, void* d_ws, size_t ws_size,
                              hipStream_t stream) {
    const float* x     = (const float*)d_in[0];
    const int*   esrc  = (const int*)d_in[1];
    const int*   edst  = (const int*)d_in[2];
    const float* W0    = (const float*)d_in[4];
    const float* b0    = (const float*)d_in[5];
    const float* Wr    = (const float*)d_in[6];
    const float* br    = (const float*)d_in[7];
    const float* gamma = (const float*)d_in[8];
    const float* beta  = (const float*)d_in[9];
    const float* Watt  = (const float*)d_in[10];
    float* out = (float*)d_out;
    float* ws  = (float*)d_ws;

    // workspace layout (float units), ~51MB
    int*   cnt     = (int*)(ws + 0);             // 32768
    float* dinv    = ws + 32768;                 // 32768
    float* stats   = ws + 65536;                 // 2560
    float* tgbuf   = ws + 68096;                 // 8192
    float* meansum = ws + 76288;                 // 8192
    float* gf      = ws + 84480;                 // 8192
    unsigned short* Wt_h  = (unsigned short*)(ws + 92672);     // 147456 sh
    unsigned short* Wt_l  = (unsigned short*)(ws + 166400);
    unsigned short* hwT_h = (unsigned short*)(ws + 240128);    // 4.19M sh
    unsigned short* hwT_l = (unsigned short*)(ws + 2337280);
    unsigned char*  Mu8   = (unsigned char*)(ws + 4434432);    // NN*512 u8 = 16.7MB
    float* pre     = ws + 8628736;               // NN*128 fp32
    // end: 12823040 floats = 51.3MB

    hipMemsetAsync(cnt, 0, NN * sizeof(int), stream);
    hipMemsetAsync(stats, 0, LL * 256 * sizeof(float), stream);
    hipMemsetAsync(meansum, 0, BG * 128 * sizeof(float), stream);
    hipMemsetAsync(gf, 0, BG * 128 * sizeof(float), stream);
    hipMemsetAsync(Mu8, 0, (size_t)NN * 512, stream);

    k_histM<<<EE / 256, 256, 0, stream>>>(esrc, edst, (unsigned int*)Mu8, cnt);
    k_diag<<<NN / 256, 256, 0, stream>>>(Mu8);
    k_dinv<<<NN / 256, 256, 0, stream>>>(cnt, dinv);
    k_wt<<<9 * 16384 / 256, 256, 0, stream>>>(Wr, Wt_h, Wt_l);
    k_l0<<<128 * (NN / 8) / 256, 256, 0, stream>>>(x, W0, dinv, hwT_h, hwT_l);

    for (int l = 0; l < LL; l++) {
        const float* bias = (l == 0) ? b0 : br + (l - 1) * DD;
        k_aggmm<<<NN / 128, 256, 0, stream>>>(Mu8, hwT_h, hwT_l, dinv, bias,
                                              pre, stats + l * 256);
        if (l < LL - 1)
            k_mmT<<<NN / 64, 256, 0, stream>>>(pre, stats + l * 256, gamma + l * DD,
                                               beta + l * DD, dinv, Wt_h + l * 16384,
                                               Wt_l + l * 16384, hwT_h, hwT_l);
        else
            k_bn_pool<<<NN / 64, 256, 0, stream>>>(pre, stats + l * 256, gamma + l * DD,
                                                   beta + l * DD, meansum);
    }
    k_tg<<<BG, 128, 0, stream>>>(meansum, Watt, tgbuf);
    k_coef_gf<<<NN / 64, 256, 0, stream>>>(pre, tgbuf, gf);
    k_out<<<NN * 64 / 256, 256, 0, stream>>>(pre, gf, out);
}